// Round 3
// baseline (800.559 us; speedup 1.0000x reference)
//
#include <hip/hip_runtime.h>
#include <stdint.h>

// SpikingTransformer block, bf16x3 split-precision MFMA version.
// B=16, N=1024, C=512, H=8, hd=64, HID=2048, M=B*N=16384.
//  - attn reassociated: o = relu(0.125 * q @ (k^T @ v)), k^T v is 64x64/(b,h)
//  - BN folded to per-channel scale/shift
//  - all activations stored as bf16 hi/lo plane pairs (Dekker split);
//    GEMMs compute Ahi*Bhi + Ahi*Blo + Alo*Bhi with fp32 MFMA accum (~1e-5 rel)
//  - weights pre-packed into MFMA B-fragment order (coalesced global frag loads)
//  - A staged to LDS via global_load_lds(16B), source pre-swizzled so frag
//    ds_read_b128 is 2-way-conflict max (free); swizzle is the same involution
//    on both sides (G21 both-sides-or-neither)
//
// Workspace (bytes), peak 176MB at f1 time:
//   0..12MB    packed weight planes (q,k,v,p: 0.5MB/plane; f1,f2: 2MB/plane)
//   12MB       folded BN sc/sh arrays
//   16/32MB    xs hi/lo   (x split)      -> reused as x1 hi/lo
//   48/64MB    qp hi/lo                  -> dead after attn
//   80/96MB    kp hi/lo   (o aliases)    -> dead after p-GEMM
//   112/128MB  vp hi/lo                  -> dead after attn
//   48MB       h hi plane (64MB, spans 48..112, over dead q/k planes)
//   112MB      h lo plane (64MB, spans 112..176, over dead v planes)

typedef __attribute__((ext_vector_type(8))) short short8;
typedef __attribute__((ext_vector_type(4))) short short4v;
typedef __attribute__((ext_vector_type(4))) float f32x4;

#define MFMA_BF16 __builtin_amdgcn_mfma_f32_16x16x32_bf16

__device__ __forceinline__ float bf2f(unsigned short u) {
    return __uint_as_float(((unsigned int)u) << 16);
}
__device__ __forceinline__ unsigned short f2bf_rne(float f) {
    unsigned int b = __float_as_uint(f);
    return (unsigned short)((b + 0x7fffu + ((b >> 16) & 1u)) >> 16);
}
// Dekker split: x = hi + lo with hi = truncate-to-bf16(x) (exact subtraction)
__device__ __forceinline__ void split2(float x, unsigned short& h, unsigned short& l) {
    unsigned int b = __float_as_uint(x);
    unsigned int hb = b & 0xffff0000u;
    h = (unsigned short)(hb >> 16);
    l = f2bf_rne(x - __uint_as_float(hb));
}
__device__ __forceinline__ void gl_lds16(const void* g, void* l) {
    __builtin_amdgcn_global_load_lds(
        (const __attribute__((address_space(1))) void*)g,
        (__attribute__((address_space(3))) void*)l, 16, 0, 0);
}

// ---------------- BN fold ----------------
__global__ __launch_bounds__(256) void prep_bn(
    const float* __restrict__ bias, const float* __restrict__ g,
    const float* __restrict__ be,   const float* __restrict__ m,
    const float* __restrict__ v,
    float* __restrict__ sc, float* __restrict__ sh, int n)
{
    int i = blockIdx.x * 256 + threadIdx.x;
    if (i < n) {
        float s = g[i] * rsqrtf(v[i] + 1e-5f);
        sc[i] = s;
        sh[i] = (bias[i] - m[i]) * s + be[i];
    }
}

// ---------------- split x into planes ----------------
__global__ __launch_bounds__(256) void split_x(
    const float* __restrict__ in, unsigned short* __restrict__ ph,
    unsigned short* __restrict__ pl, int n4)
{
    int i = blockIdx.x * 256 + threadIdx.x;
    if (i >= n4) return;
    float4 v = ((const float4*)in)[i];
    unsigned short h0, h1, h2, h3, l0, l1, l2, l3;
    split2(v.x, h0, l0); split2(v.y, h1, l1);
    split2(v.z, h2, l2); split2(v.w, h3, l3);
    ((short4v*)ph)[i] = short4v{(short)h0, (short)h1, (short)h2, (short)h3};
    ((short4v*)pl)[i] = short4v{(short)l0, (short)l1, (short)l2, (short)l3};
}

// -------- pack W (NxK fp32) into MFMA B-fragment order, hi/lo planes --------
// fragment block (n16, kc): 64 lanes x 8 elems; lane l -> W[n16*16+(l&15)]
// [kc*32 + (l>>4)*8 + j]; flat = ((n16*(K/32)+kc)<<9) + l*8 + j
__global__ __launch_bounds__(256) void prep_w(
    const float* __restrict__ W, unsigned short* __restrict__ ph,
    unsigned short* __restrict__ pl, int N, int K)
{
    int tid = blockIdx.x * 256 + threadIdx.x;
    int KC = K >> 5;
    int total = (N >> 4) * KC * 64;
    if (tid >= total) return;
    int lane = tid & 63;
    int blk  = tid >> 6;
    int kc   = blk % KC;
    int n16  = blk / KC;
    int n  = (n16 << 4) + (lane & 15);
    int k0 = (kc << 5) + ((lane >> 4) << 3);
    const float* src = W + (size_t)n * K + k0;
    size_t dst = ((size_t)blk << 9) + (size_t)lane * 8;
#pragma unroll
    for (int j = 0; j < 8; ++j) {
        unsigned short hh, ll;
        split2(src[j], hh, ll);
        ph[dst + j] = hh;
        pl[dst + j] = ll;
    }
}

// ---------------- bf16x3 GEMM + BN + ReLU (+ residual) ----------------
// out = relu((A @ W^T) * sc + sh) [+ res];  A: MxK planes, W packed planes.
// RESMODE: 0 none, 1 fp32 res, 2 plane res. OUTF32: write fp32, else planes.
template<int RESMODE, bool OUTF32>
__global__ __launch_bounds__(256) void gemm3(
    const unsigned short* __restrict__ Ah_g, const unsigned short* __restrict__ Al_g,
    const unsigned short* __restrict__ Wh_g, const unsigned short* __restrict__ Wl_g,
    const float* __restrict__ sc, const float* __restrict__ sh,
    const float* __restrict__ resf,
    const unsigned short* __restrict__ resh, const unsigned short* __restrict__ resl,
    float* __restrict__ outf, unsigned short* __restrict__ outh,
    unsigned short* __restrict__ outl, int M, int N, int K)
{
    __shared__ unsigned short Ah[128 * 32];
    __shared__ unsigned short Al[128 * 32];

    const int t    = threadIdx.x;
    const int lane = t & 63;
    const int w    = t >> 6;        // 4 waves, 2x2 over 128x128
    const int wm   = w >> 1, wn = w & 1;
    const int m0   = blockIdx.y * 128;
    const int n0   = blockIdx.x * 128;
    const int KC   = K >> 5;

    // A staging: wave w stages rows [(w*2+c)*16, +16), c=0,1; lane -> row l>>2,
    // phys unit l&3. Source pre-swizzled: logical kb = punit ^ ((row>>1)&3).
    const int srow0 = (w * 2 + 0) * 16 + (lane >> 2);
    const int srow1 = (w * 2 + 1) * 16 + (lane >> 2);
    const int kb0 = (lane & 3) ^ ((srow0 >> 1) & 3);
    const int kb1 = (lane & 3) ^ ((srow1 >> 1) & 3);
    const unsigned short* sAh0 = Ah_g + (size_t)(m0 + srow0) * K + kb0 * 8;
    const unsigned short* sAh1 = Ah_g + (size_t)(m0 + srow1) * K + kb1 * 8;
    const unsigned short* sAl0 = Al_g + (size_t)(m0 + srow0) * K + kb0 * 8;
    const unsigned short* sAl1 = Al_g + (size_t)(m0 + srow1) * K + kb1 * 8;
    unsigned short* dAh0 = &Ah[(w * 2 + 0) * 512];  // wave-uniform LDS bases
    unsigned short* dAh1 = &Ah[(w * 2 + 1) * 512];
    unsigned short* dAl0 = &Al[(w * 2 + 0) * 512];
    unsigned short* dAl1 = &Al[(w * 2 + 1) * 512];

    // B fragment pointers (advance 512 elems per kc)
    const unsigned short* pBh[4];
    const unsigned short* pBl[4];
#pragma unroll
    for (int nf = 0; nf < 4; ++nf) {
        const int n16 = (n0 >> 4) + wn * 4 + nf;
        pBh[nf] = Wh_g + (((size_t)n16 * KC) << 9) + (size_t)lane * 8;
        pBl[nf] = Wl_g + (((size_t)n16 * KC) << 9) + (size_t)lane * 8;
    }

    // A fragment LDS offsets (shorts). row = wm*64+mi*16+(lane&15);
    // phys unit = (lane>>4) ^ ((row>>1)&3) = (lane>>4) ^ (((lane&15)>>1)&3)
    const int fr = lane & 15, fk = lane >> 4;
    const int funit = fk ^ ((fr >> 1) & 3);
    int aoff[4];
#pragma unroll
    for (int mi = 0; mi < 4; ++mi)
        aoff[mi] = (wm * 64 + mi * 16 + fr) * 32 + funit * 8;

    f32x4 acc[4][4];
#pragma unroll
    for (int i = 0; i < 4; ++i)
#pragma unroll
        for (int j = 0; j < 4; ++j) acc[i][j] = f32x4{0.f, 0.f, 0.f, 0.f};

    for (int kc = 0; kc < KC; ++kc) {
        __syncthreads();                 // lgkmcnt(0) drain: prev-tile ds_reads done
        gl_lds16(sAh0, dAh0); gl_lds16(sAh1, dAh1);
        gl_lds16(sAl0, dAl0); gl_lds16(sAl1, dAl1);
        sAh0 += 32; sAh1 += 32; sAl0 += 32; sAl1 += 32;

        short8 bh[4], bl[4];
#pragma unroll
        for (int nf = 0; nf < 4; ++nf) {
            bh[nf] = *(const short8*)pBh[nf];
            bl[nf] = *(const short8*)pBl[nf];
            pBh[nf] += 512; pBl[nf] += 512;
        }
        __syncthreads();                 // vmcnt(0) drain: LDS tile valid

        short8 ah[4], al[4];
#pragma unroll
        for (int mi = 0; mi < 4; ++mi) {
            ah[mi] = *(const short8*)&Ah[aoff[mi]];
            al[mi] = *(const short8*)&Al[aoff[mi]];
        }
#pragma unroll
        for (int mi = 0; mi < 4; ++mi)
#pragma unroll
            for (int nf = 0; nf < 4; ++nf) {
                acc[mi][nf] = MFMA_BF16(ah[mi], bh[nf], acc[mi][nf], 0, 0, 0);
                acc[mi][nf] = MFMA_BF16(ah[mi], bl[nf], acc[mi][nf], 0, 0, 0);
                acc[mi][nf] = MFMA_BF16(al[mi], bh[nf], acc[mi][nf], 0, 0, 0);
            }
    }

    // epilogue: C/D layout col = lane&15, row = (lane>>4)*4 + reg (m89)
    const int erow4 = fk * 4;
#pragma unroll
    for (int nf = 0; nf < 4; ++nf) {
        const int col = n0 + wn * 64 + nf * 16 + fr;
        const float scv = sc[col], shv = sh[col];
#pragma unroll
        for (int mi = 0; mi < 4; ++mi) {
            const int rbase = m0 + wm * 64 + mi * 16 + erow4;
#pragma unroll
            for (int r = 0; r < 4; ++r) {
                const size_t idx = (size_t)(rbase + r) * N + col;
                float z = fmaf(acc[mi][nf][r], scv, shv);
                z = fmaxf(z, 0.f);
                if (RESMODE == 1) z += resf[idx];
                if (RESMODE == 2) z += bf2f(resh[idx]) + bf2f(resl[idx]);
                if (OUTF32) {
                    outf[idx] = z;
                } else {
                    unsigned short hh, ll;
                    split2(z, hh, ll);
                    outh[idx] = hh;
                    outl[idx] = ll;
                }
            }
        }
    }
}

// ---------------- attention: o = relu(0.125 * q @ (k^T v)) ----------------
// per-(b,h) block; reads plane pairs, writes o planes (aliasing k planes:
// block (b,h) writes exactly the row/col slice only it reads -- exclusive).
__global__ __launch_bounds__(256) void attn_kernel(
    const unsigned short* __restrict__ qh, const unsigned short* __restrict__ ql,
    const unsigned short* __restrict__ kh, const unsigned short* __restrict__ kl,
    const unsigned short* __restrict__ vh, const unsigned short* __restrict__ vl,
    unsigned short* __restrict__ oh, unsigned short* __restrict__ ol)
{
    __shared__ float ks[64][68];
    __shared__ float vs[64][68];
    __shared__ float kv[64][68];

    const int bh_ = blockIdx.x;
    const int b = bh_ >> 3;
    const int h = bh_ & 7;
    const size_t base = (size_t)b * 1024 * 512 + (size_t)h * 64;
    const int t = threadIdx.x;

    float acc[4][4] = {{0.f}};
    const int ti = (t >> 4) * 4;
    const int tj = (t & 15) * 4;
    const int lr = t >> 2;          // loader row 0..63
    const int c0 = (t & 3) * 16;    // loader col group

    for (int n0 = 0; n0 < 1024; n0 += 64) {
        __syncthreads();
        const size_t off = base + (size_t)(n0 + lr) * 512 + c0;
        short8 ka0 = *(const short8*)(kh + off);
        short8 ka1 = *(const short8*)(kh + off + 8);
        short8 kb_ = *(const short8*)(kl + off);
        short8 kb1 = *(const short8*)(kl + off + 8);
        short8 va0 = *(const short8*)(vh + off);
        short8 va1 = *(const short8*)(vh + off + 8);
        short8 vb_ = *(const short8*)(vl + off);
        short8 vb1 = *(const short8*)(vl + off + 8);
#pragma unroll
        for (int j = 0; j < 8; ++j) {
            ks[lr][c0 + j]     = bf2f((unsigned short)ka0[j]) + bf2f((unsigned short)kb_[j]);
            ks[lr][c0 + 8 + j] = bf2f((unsigned short)ka1[j]) + bf2f((unsigned short)kb1[j]);
            vs[lr][c0 + j]     = bf2f((unsigned short)va0[j]) + bf2f((unsigned short)vb_[j]);
            vs[lr][c0 + 8 + j] = bf2f((unsigned short)va1[j]) + bf2f((unsigned short)vb1[j]);
        }
        __syncthreads();
#pragma unroll 8
        for (int n = 0; n < 64; ++n) {
            float ka[4], va[4];
#pragma unroll
            for (int a = 0; a < 4; ++a) ka[a] = ks[n][ti + a];
#pragma unroll
            for (int c = 0; c < 4; ++c) va[c] = vs[n][tj + c];
#pragma unroll
            for (int a = 0; a < 4; ++a)
#pragma unroll
                for (int c = 0; c < 4; ++c)
                    acc[a][c] = fmaf(ka[a], va[c], acc[a][c]);
        }
    }
#pragma unroll
    for (int a = 0; a < 4; ++a)
#pragma unroll
        for (int c = 0; c < 4; ++c)
            kv[ti + a][tj + c] = acc[a][c] * 0.125f;
    __syncthreads();

    const int qr = t >> 4;
    const int qc = (t & 15) * 4;
    for (int r0 = 0; r0 < 1024; r0 += 16) {
        __syncthreads();
        const size_t off = base + (size_t)(r0 + qr) * 512 + qc;
        short4v qhv = *(const short4v*)(qh + off);
        short4v qlv = *(const short4v*)(ql + off);
#pragma unroll
        for (int j = 0; j < 4; ++j)
            ks[qr][qc + j] = bf2f((unsigned short)qhv[j]) + bf2f((unsigned short)qlv[j]);
        __syncthreads();
        float oa[4] = {0.f, 0.f, 0.f, 0.f};
#pragma unroll 8
        for (int i = 0; i < 64; ++i) {
            const float qv = ks[qr][i];
#pragma unroll
            for (int c = 0; c < 4; ++c)
                oa[c] = fmaf(qv, kv[i][qc + c], oa[c]);
        }
        unsigned short hh[4], ll[4];
#pragma unroll
        for (int c = 0; c < 4; ++c) split2(fmaxf(oa[c], 0.f), hh[c], ll[c]);
        *(short4v*)(oh + off) = short4v{(short)hh[0], (short)hh[1], (short)hh[2], (short)hh[3]};
        *(short4v*)(ol + off) = short4v{(short)ll[0], (short)ll[1], (short)ll[2], (short)ll[3]};
    }
}

extern "C" void kernel_launch(void* const* d_in, const int* in_sizes, int n_in,
                              void* d_out, int out_size, void* d_ws, size_t ws_size,
                              hipStream_t stream)
{
    (void)in_sizes; (void)n_in; (void)out_size; (void)ws_size;
    const float* x = (const float*)d_in[0];
    auto P = [&](int i) { return (const float*)d_in[i]; };
    // inputs: x:0; per layer (w,b,g,be,m,v): q:1 k:7 v:13 p:19 f1:25 f2:31

    char* wsb = (char*)d_ws;
    const size_t MB = 1024 * 1024;
    auto US = [&](size_t off) { return (unsigned short*)(wsb + off); };

    unsigned short* Wq_h = US(0);           unsigned short* Wq_l = US(MB / 2);
    unsigned short* Wk_h = US(1 * MB);      unsigned short* Wk_l = US(3 * MB / 2);
    unsigned short* Wv_h = US(2 * MB);      unsigned short* Wv_l = US(5 * MB / 2);
    unsigned short* Wp_h = US(3 * MB);      unsigned short* Wp_l = US(7 * MB / 2);
    unsigned short* W1_h = US(4 * MB);      unsigned short* W1_l = US(6 * MB);
    unsigned short* W2_h = US(8 * MB);      unsigned short* W2_l = US(10 * MB);

    float* bn = (float*)(wsb + 12 * MB);
    float* sc_q = bn;            float* sh_q = bn + 2048;
    float* sc_k = bn + 4096;     float* sh_k = bn + 6144;
    float* sc_v = bn + 8192;     float* sh_v = bn + 10240;
    float* sc_p = bn + 12288;    float* sh_p = bn + 14336;
    float* sc_1 = bn + 16384;    float* sh_1 = bn + 18432;  // 2048-wide
    float* sc_2 = bn + 20480;    float* sh_2 = bn + 22528;

    unsigned short* xs_h = US(16 * MB);     unsigned short* xs_l = US(32 * MB);
    unsigned short* qp_h = US(48 * MB);     unsigned short* qp_l = US(64 * MB);
    unsigned short* kp_h = US(80 * MB);     unsigned short* kp_l = US(96 * MB);
    unsigned short* vp_h = US(112 * MB);    unsigned short* vp_l = US(128 * MB);
    unsigned short* x1_h = xs_h;            unsigned short* x1_l = xs_l;   // xs dead
    unsigned short* hp_h = US(48 * MB);     // 64MB, over q/k planes (dead)
    unsigned short* hp_l = US(112 * MB);    // 64MB, over v planes + fresh

    prep_bn<<<2, 256, 0, stream>>>(P(2),  P(3),  P(4),  P(5),  P(6),  sc_q, sh_q, 512);
    prep_bn<<<2, 256, 0, stream>>>(P(8),  P(9),  P(10), P(11), P(12), sc_k, sh_k, 512);
    prep_bn<<<2, 256, 0, stream>>>(P(14), P(15), P(16), P(17), P(18), sc_v, sh_v, 512);
    prep_bn<<<2, 256, 0, stream>>>(P(20), P(21), P(22), P(23), P(24), sc_p, sh_p, 512);
    prep_bn<<<8, 256, 0, stream>>>(P(26), P(27), P(28), P(29), P(30), sc_1, sh_1, 2048);
    prep_bn<<<2, 256, 0, stream>>>(P(32), P(33), P(34), P(35), P(36), sc_2, sh_2, 512);

    split_x<<<8192, 256, 0, stream>>>(x, xs_h, xs_l, 16384 * 512 / 4);

    prep_w<<<128, 256, 0, stream>>>(P(1),  Wq_h, Wq_l, 512, 512);
    prep_w<<<128, 256, 0, stream>>>(P(7),  Wk_h, Wk_l, 512, 512);
    prep_w<<<128, 256, 0, stream>>>(P(13), Wv_h, Wv_l, 512, 512);
    prep_w<<<128, 256, 0, stream>>>(P(19), Wp_h, Wp_l, 512, 512);
    prep_w<<<512, 256, 0, stream>>>(P(25), W1_h, W1_l, 2048, 512);
    prep_w<<<512, 256, 0, stream>>>(P(31), W2_h, W2_l, 512, 2048);

    const dim3 blk(256);
    const dim3 g512(4, 128);    // N=512:  (512/128, 16384/128)
    const dim3 g2048(16, 128);  // N=2048

    gemm3<0, false><<<g512, blk, 0, stream>>>(xs_h, xs_l, Wq_h, Wq_l, sc_q, sh_q,
        nullptr, nullptr, nullptr, nullptr, qp_h, qp_l, 16384, 512, 512);
    gemm3<0, false><<<g512, blk, 0, stream>>>(xs_h, xs_l, Wk_h, Wk_l, sc_k, sh_k,
        nullptr, nullptr, nullptr, nullptr, kp_h, kp_l, 16384, 512, 512);
    gemm3<0, false><<<g512, blk, 0, stream>>>(xs_h, xs_l, Wv_h, Wv_l, sc_v, sh_v,
        nullptr, nullptr, nullptr, nullptr, vp_h, vp_l, 16384, 512, 512);

    attn_kernel<<<128, blk, 0, stream>>>(qp_h, qp_l, kp_h, kp_l, vp_h, vp_l,
                                         kp_h, kp_l);   // o -> k planes

    // x1 = x + relu(bn(o @ p_w^T))   (writes over xs planes)
    gemm3<1, false><<<g512, blk, 0, stream>>>(kp_h, kp_l, Wp_h, Wp_l, sc_p, sh_p,
        x, nullptr, nullptr, nullptr, x1_h, x1_l, 16384, 512, 512);

    // h = relu(bn(x1 @ f1_w^T))
    gemm3<0, false><<<g2048, blk, 0, stream>>>(x1_h, x1_l, W1_h, W1_l, sc_1, sh_1,
        nullptr, nullptr, nullptr, nullptr, hp_h, hp_l, 16384, 2048, 512);

    // out = x1 + relu(bn(h @ f2_w^T))   (fp32 to d_out)
    gemm3<2, true><<<g512, blk, 0, stream>>>(hp_h, hp_l, W2_h, W2_l, sc_2, sh_2,
        nullptr, x1_h, x1_l, (float*)d_out, nullptr, nullptr, 16384, 512, 2048);
}

// Round 5
// 440.473 us; speedup vs baseline: 1.8175x; 1.8175x over previous
//
#include <hip/hip_runtime.h>
#include <stdint.h>

// SpikingTransformer block, plain-bf16 MFMA version (tolerance absmax<=0.5;
// bf16x3 measured pass at R3, bf16 single predicted ~0.05-0.2).
// B=16, N=1024, C=512, H=8, hd=64, HID=2048, M=B*N=16384.
//  - attn reassociated: o = relu(0.125 * q @ (k^T @ v)), k^T v is 64x64/(b,h)
//  - BN folded to per-channel scale/shift
//  - fused QKV GEMM (N=1536): x read once, grid 1536 (6 blocks/CU)
//  - N=512 GEMMs use 64-wide tiles: grid 1024 (4 blocks/CU) vs 512 (2/CU)
//  - weights pre-packed to MFMA B-frag order; A staged via global_load_lds(16B)
//    with source pre-swizzle == read swizzle (verified: 0 bank conflicts R3)
//  - bijective XCD swizzle on linearized block id (all grids %8==0)
//
// Workspace (MB offsets): 0 Wqkv(1.5) | 2 Wp(.5) | 3 W1(2) | 5 W2(2) | 7 BN |
//   8 xb(16.8)->x1 | 25 qb(16.8, o aliases) | 42 kb | 59 vb | 76 h(67.1)->143
//   (h overlays kb+vb, both dead post-attn). Peak ~143 MB.

typedef __attribute__((ext_vector_type(8))) short short8;
typedef __attribute__((ext_vector_type(4))) short short4v;
typedef __attribute__((ext_vector_type(4))) float f32x4;

#define MFMA_BF16 __builtin_amdgcn_mfma_f32_16x16x32_bf16

__device__ __forceinline__ float bf2f(unsigned short u) {
    return __uint_as_float(((unsigned int)u) << 16);
}
__device__ __forceinline__ unsigned short f2bf(float f) {
    unsigned int b = __float_as_uint(f);
    return (unsigned short)((b + 0x7fffu + ((b >> 16) & 1u)) >> 16);
}
__device__ __forceinline__ void gl_lds16(const void* g, void* l) {
    __builtin_amdgcn_global_load_lds(
        (const __attribute__((address_space(1))) void*)g,
        (__attribute__((address_space(3))) void*)l, 16, 0, 0);
}

// ---------------- BN fold ----------------
__global__ __launch_bounds__(256) void prep_bn(
    const float* __restrict__ bias, const float* __restrict__ g,
    const float* __restrict__ be,   const float* __restrict__ m,
    const float* __restrict__ v,
    float* __restrict__ sc, float* __restrict__ sh, int n)
{
    int i = blockIdx.x * 256 + threadIdx.x;
    if (i < n) {
        float s = g[i] * rsqrtf(v[i] + 1e-5f);
        sc[i] = s;
        sh[i] = (bias[i] - m[i]) * s + be[i];
    }
}

// ---------------- x -> bf16 ----------------
__global__ __launch_bounds__(256) void to_bf16(
    const float* __restrict__ in, unsigned short* __restrict__ out, int n8)
{
    int i = blockIdx.x * 256 + threadIdx.x;
    if (i >= n8) return;
    const float4* p = (const float4*)in + (size_t)i * 2;
    float4 a = p[0], b = p[1];
    short8 r = {(short)f2bf(a.x), (short)f2bf(a.y), (short)f2bf(a.z), (short)f2bf(a.w),
                (short)f2bf(b.x), (short)f2bf(b.y), (short)f2bf(b.z), (short)f2bf(b.w)};
    ((short8*)out)[i] = r;
}

// -------- pack W (NxK fp32) into MFMA B-fragment order --------
// frag block (n16,kc): lane l -> W[n16*16+(l&15)][kc*32+(l>>4)*8+j];
// flat = ((n16*(K/32)+kc)<<9) + l*8 + j
__global__ __launch_bounds__(256) void prep_w(
    const float* __restrict__ W, unsigned short* __restrict__ ph, int N, int K)
{
    int tid = blockIdx.x * 256 + threadIdx.x;
    int KC = K >> 5;
    int total = (N >> 4) * KC * 64;
    if (tid >= total) return;
    int lane = tid & 63;
    int blk  = tid >> 6;
    int kc   = blk % KC;
    int n16  = blk / KC;
    int n  = (n16 << 4) + (lane & 15);
    int k0 = (kc << 5) + ((lane >> 4) << 3);
    const float* src = W + (size_t)n * K + k0;
    size_t dst = ((size_t)blk << 9) + (size_t)lane * 8;
#pragma unroll
    for (int j = 0; j < 8; ++j) ph[dst + j] = f2bf(src[j]);
}

// ---------------- bf16 GEMM + BN + ReLU (+ residual) ----------------
// out = relu((A @ W^T) * sc + sh) [+ res]
// NT: block N-tile (128 or 64), block M-tile 128, 4 waves 2x2.
// RESMODE: 0 none, 1 fp32 res, 2 bf16 res.
// OUTMODE: 0 bf16, 1 fp32, 2 qkv-split (col>>9 routes to oq/ok/ov, stride 512).
template<int NT, int RESMODE, int OUTMODE>
__global__ __launch_bounds__(256) void gemm_bf16(
    const unsigned short* __restrict__ Ag, const unsigned short* __restrict__ Wg,
    const float* __restrict__ sc, const float* __restrict__ sh,
    const float* __restrict__ resf, const unsigned short* __restrict__ resb,
    float* __restrict__ outf, unsigned short* __restrict__ outb,
    unsigned short* __restrict__ oq, unsigned short* __restrict__ ok2,
    unsigned short* __restrict__ ov, int M, int N, int K)
{
    constexpr int NF = NT / 32;            // B-frags per wave
    __shared__ unsigned short As[128 * 32];

    const int t    = threadIdx.x;
    const int lane = t & 63;
    const int w    = t >> 6;               // 4 waves, 2x2 over 128xNT
    const int wm   = w >> 1, wn = w & 1;
    const int KC   = K >> 5;

    // bijective XCD swizzle (requires nwg%8==0 -- true for all our grids)
    const int nx  = gridDim.x;
    const int nwg = nx * gridDim.y;
    int bid = blockIdx.y * nx + blockIdx.x;
    bid = (bid & 7) * (nwg >> 3) + (bid >> 3);
    const int m0 = (bid / nx) * 128;
    const int n0 = (bid % nx) * NT;

    // A staging: wave w stages rows [w*32, w*32+32), lane -> row lane>>2,
    // phys k-unit lane&3; source pre-swizzled: kb = (lane&3)^((row>>1)&3),
    // and (row>>1)&3 here reduces to (lane>>3)&3 (w,c offsets are %4==0).
    const int sr  = lane >> 2;
    const int kbu = (lane & 3) ^ ((lane >> 3) & 3);
    const unsigned short* sA0 = Ag + (size_t)(m0 + w * 32 + sr) * K + kbu * 8;
    const unsigned short* sA1 = sA0 + (size_t)16 * K;
    unsigned short* dA0 = &As[(w * 32) * 32];        // wave-uniform LDS base
    unsigned short* dA1 = &As[(w * 32 + 16) * 32];

    // B fragment pointers (advance 512 elems per kc)
    const unsigned short* pB[NF];
#pragma unroll
    for (int nf = 0; nf < NF; ++nf) {
        const int n16 = (n0 >> 4) + wn * (NT / 32) + nf;
        pB[nf] = Wg + (((size_t)n16 * KC) << 9) + (size_t)lane * 8;
    }

    // A fragment LDS offsets. row = wm*64+mi*16+fr; phys unit = fk^((fr>>1)&3)
    const int fr = lane & 15, fk = lane >> 4;
    const int funit = fk ^ ((fr >> 1) & 3);
    int aoff[4];
#pragma unroll
    for (int mi = 0; mi < 4; ++mi)
        aoff[mi] = (wm * 64 + mi * 16 + fr) * 32 + funit * 8;

    f32x4 acc[4][NF];
#pragma unroll
    for (int i = 0; i < 4; ++i)
#pragma unroll
        for (int j = 0; j < NF; ++j) acc[i][j] = f32x4{0.f, 0.f, 0.f, 0.f};

    for (int kc = 0; kc < KC; ++kc) {
        __syncthreads();                   // lgkmcnt drain: prev-tile reads done
        gl_lds16(sA0, dA0); gl_lds16(sA1, dA1);
        sA0 += 32; sA1 += 32;

        short8 bh[NF];
#pragma unroll
        for (int nf = 0; nf < NF; ++nf) {
            bh[nf] = *(const short8*)pB[nf];
            pB[nf] += 512;
        }
        __syncthreads();                   // vmcnt drain: LDS tile valid

        short8 ah[4];
#pragma unroll
        for (int mi = 0; mi < 4; ++mi) ah[mi] = *(const short8*)&As[aoff[mi]];
#pragma unroll
        for (int mi = 0; mi < 4; ++mi)
#pragma unroll
            for (int nf = 0; nf < NF; ++nf)
                acc[mi][nf] = MFMA_BF16(ah[mi], bh[nf], acc[mi][nf], 0, 0, 0);
    }

    // epilogue: C/D layout col = lane&15, row = (lane>>4)*4 + reg (m89)
    const int erow4 = fk * 4;
#pragma unroll
    for (int nf = 0; nf < NF; ++nf) {
        const int col = n0 + wn * (NT / 2) + nf * 16 + fr;
        const float scv = sc[col], shv = sh[col];
        unsigned short* qsplit = nullptr;
        int lc = 0;
        if (OUTMODE == 2) {
            const int tsel = col >> 9;     // uniform within an nf 16-col chunk
            qsplit = (tsel == 0) ? oq : (tsel == 1) ? ok2 : ov;
            lc = col & 511;
        }
#pragma unroll
        for (int mi = 0; mi < 4; ++mi) {
            const int rbase = m0 + wm * 64 + mi * 16 + erow4;
#pragma unroll
            for (int r = 0; r < 4; ++r) {
                const size_t row = (size_t)(rbase + r);
                float z = fmaf(acc[mi][nf][r], scv, shv);
                z = fmaxf(z, 0.f);
                if (RESMODE == 1) z += resf[row * N + col];
                if (RESMODE == 2) z += bf2f(resb[row * N + col]);
                if (OUTMODE == 0)      outb[row * N + col] = f2bf(z);
                else if (OUTMODE == 1) outf[row * N + col] = z;
                else                   qsplit[row * 512 + lc] = f2bf(z);
            }
        }
    }
}

// ---------------- attention: o = relu(0.125 * q @ (k^T v)) ----------------
// grid (128, 2): block (bh, z) computes full ktv, then q-rows [z*512, z*512+512).
// o aliases q: each block reads/writes only its own (row-range x head-cols).
__global__ __launch_bounds__(256) void attn_kernel(
    const unsigned short* __restrict__ q, const unsigned short* __restrict__ k,
    const unsigned short* __restrict__ v, unsigned short* __restrict__ o)
{
    __shared__ float ks[64][68];
    __shared__ float vs[64][68];
    __shared__ float kv[64][68];

    const int bh = blockIdx.x;
    const int z  = blockIdx.y;
    const int b = bh >> 3;
    const int h = bh & 7;
    const size_t base = (size_t)b * 1024 * 512 + (size_t)h * 64;
    const int t = threadIdx.x;

    float acc[4][4] = {{0.f}};
    const int ti = (t >> 4) * 4;
    const int tj = (t & 15) * 4;
    const int lr = t >> 2;          // loader row 0..63
    const int c0 = (t & 3) * 16;    // loader col group

    for (int n0 = 0; n0 < 1024; n0 += 64) {
        __syncthreads();
        const size_t off = base + (size_t)(n0 + lr) * 512 + c0;
        short8 k0 = *(const short8*)(k + off);
        short8 k1 = *(const short8*)(k + off + 8);
        short8 v0 = *(const short8*)(v + off);
        short8 v1 = *(const short8*)(v + off + 8);
#pragma unroll
        for (int j = 0; j < 8; ++j) {
            ks[lr][c0 + j]     = bf2f((unsigned short)k0[j]);
            ks[lr][c0 + 8 + j] = bf2f((unsigned short)k1[j]);
            vs[lr][c0 + j]     = bf2f((unsigned short)v0[j]);
            vs[lr][c0 + 8 + j] = bf2f((unsigned short)v1[j]);
        }
        __syncthreads();
#pragma unroll 8
        for (int n = 0; n < 64; ++n) {
            float ka[4], va[4];
#pragma unroll
            for (int a = 0; a < 4; ++a) ka[a] = ks[n][ti + a];
#pragma unroll
            for (int c = 0; c < 4; ++c) va[c] = vs[n][tj + c];
#pragma unroll
            for (int a = 0; a < 4; ++a)
#pragma unroll
                for (int c = 0; c < 4; ++c)
                    acc[a][c] = fmaf(ka[a], va[c], acc[a][c]);
        }
    }
#pragma unroll
    for (int a = 0; a < 4; ++a)
#pragma unroll
        for (int c = 0; c < 4; ++c)
            kv[ti + a][tj + c] = acc[a][c] * 0.125f;
    __syncthreads();

    const int qr = t >> 4;
    const int qc = (t & 15) * 4;
    for (int r0 = z * 512; r0 < z * 512 + 512; r0 += 16) {
        __syncthreads();
        const size_t off = base + (size_t)(r0 + qr) * 512 + qc;
        short4v qv = *(const short4v*)(q + off);
#pragma unroll
        for (int j = 0; j < 4; ++j) ks[qr][qc + j] = bf2f((unsigned short)qv[j]);
        __syncthreads();
        float oa[4] = {0.f, 0.f, 0.f, 0.f};
#pragma unroll 8
        for (int i = 0; i < 64; ++i) {
            const float qs = ks[qr][i];
#pragma unroll
            for (int c = 0; c < 4; ++c)
                oa[c] = fmaf(qs, kv[i][qc + c], oa[c]);
        }
        *(short4v*)(o + off) = short4v{
            (short)f2bf(fmaxf(oa[0], 0.f)), (short)f2bf(fmaxf(oa[1], 0.f)),
            (short)f2bf(fmaxf(oa[2], 0.f)), (short)f2bf(fmaxf(oa[3], 0.f))};
    }
}

extern "C" void kernel_launch(void* const* d_in, const int* in_sizes, int n_in,
                              void* d_out, int out_size, void* d_ws, size_t ws_size,
                              hipStream_t stream)
{
    (void)in_sizes; (void)n_in; (void)out_size; (void)ws_size;
    const float* x = (const float*)d_in[0];
    auto P = [&](int i) { return (const float*)d_in[i]; };
    // inputs: x:0; per layer (w,b,g,be,m,v): q:1 k:7 v:13 p:19 f1:25 f2:31

    char* wsb = (char*)d_ws;
    const size_t MB = 1024 * 1024;
    auto US = [&](size_t off) { return (unsigned short*)(wsb + off); };

    unsigned short* Wqkv = US(0);          // 1536x512 packed, 1.5 MB
    unsigned short* Wp   = US(2 * MB);     // 0.5 MB
    unsigned short* W1   = US(3 * MB);     // 2 MB
    unsigned short* W2   = US(5 * MB);     // 2 MB

    float* bn = (float*)(wsb + 7 * MB);
    float* sc_qkv = bn;          float* sh_qkv = bn + 1536;
    float* sc_p = bn + 3072;     float* sh_p = bn + 3584;
    float* sc_1 = bn + 4096;     float* sh_1 = bn + 6144;   // 2048-wide
    float* sc_2 = bn + 8192;     float* sh_2 = bn + 8704;

    unsigned short* xb = US(8 * MB);       // 16.8 MB; reused as x1
    unsigned short* qb = US(25 * MB);      // o aliases q
    unsigned short* kb = US(42 * MB);
    unsigned short* vb = US(59 * MB);
    unsigned short* hb = US(76 * MB);      // 67.1 MB over dead kb/vb, ends ~143
    unsigned short* x1 = xb;

    prep_bn<<<2, 256, 0, stream>>>(P(2),  P(3),  P(4),  P(5),  P(6),  sc_qkv,        sh_qkv,        512);
    prep_bn<<<2, 256, 0, stream>>>(P(8),  P(9),  P(10), P(11), P(12), sc_qkv + 512,  sh_qkv + 512,  512);
    prep_bn<<<2, 256, 0, stream>>>(P(14), P(15), P(16), P(17), P(18), sc_qkv + 1024, sh_qkv + 1024, 512);
    prep_bn<<<2, 256, 0, stream>>>(P(20), P(21), P(22), P(23), P(24), sc_p, sh_p, 512);
    prep_bn<<<8, 256, 0, stream>>>(P(26), P(27), P(28), P(29), P(30), sc_1, sh_1, 2048);
    prep_bn<<<2, 256, 0, stream>>>(P(32), P(33), P(34), P(35), P(36), sc_2, sh_2, 512);

    to_bf16<<<4096, 256, 0, stream>>>(x, xb, 16384 * 512 / 8);

    // pack weights; q/k/v go into one 1536-row packed buffer (n16-offset regions)
    prep_w<<<128, 256, 0, stream>>>(P(1),  Wqkv,          512, 512);
    prep_w<<<128, 256, 0, stream>>>(P(7),  Wqkv + 262144, 512, 512);
    prep_w<<<128, 256, 0, stream>>>(P(13), Wqkv + 524288, 512, 512);
    prep_w<<<128, 256, 0, stream>>>(P(19), Wp, 512, 512);
    prep_w<<<512, 256, 0, stream>>>(P(25), W1, 2048, 512);
    prep_w<<<512, 256, 0, stream>>>(P(31), W2, 512, 2048);

    const dim3 blk(256);

    // fused QKV: N=1536, grid 1536 blocks (6/CU)
    gemm_bf16<128, 0, 2><<<dim3(12, 128), blk, 0, stream>>>(
        xb, Wqkv, sc_qkv, sh_qkv, nullptr, nullptr,
        nullptr, nullptr, qb, kb, vb, 16384, 1536, 512);

    attn_kernel<<<dim3(128, 2), blk, 0, stream>>>(qb, kb, vb, qb);  // o -> qb

    // x1 = x + relu(bn(o @ p_w^T)); NT=64 -> 1024 blocks
    gemm_bf16<64, 1, 0><<<dim3(8, 128), blk, 0, stream>>>(
        qb, Wp, sc_p, sh_p, x, nullptr,
        nullptr, x1, nullptr, nullptr, nullptr, 16384, 512, 512);

    // h = relu(bn(x1 @ f1_w^T)); grid 2048 blocks
    gemm_bf16<128, 0, 0><<<dim3(16, 128), blk, 0, stream>>>(
        x1, W1, sc_1, sh_1, nullptr, nullptr,
        nullptr, hb, nullptr, nullptr, nullptr, 16384, 2048, 512);

    // out = x1 + relu(bn(h @ f2_w^T)); NT=64 -> 1024 blocks, fp32 out
    gemm_bf16<64, 2, 1><<<dim3(8, 128), blk, 0, stream>>>(
        hb, W2, sc_2, sh_2, nullptr, x1,
        (float*)d_out, nullptr, nullptr, nullptr, nullptr, 16384, 512, 2048);
}

// Round 6
// 375.936 us; speedup vs baseline: 2.1295x; 1.1717x over previous
//
#include <hip/hip_runtime.h>
#include <stdint.h>

// SpikingTransformer block, bf16 MFMA version. R6: MFMA attention.
// B=16, N=1024, C=512, H=8, hd=64, HID=2048, M=B*N=16384.
//  - attn reassociated: o = relu(0.125 * q @ (k^T @ v)), k^T v is 64x64/(b,h)
//  - attn phase A: per (b,h,half) 1-wave block MFMAs partial k^T v over 512 n,
//    emits it bf16 PACKED IN B-FRAGMENT ORDER (0.125 folded)
//  - attn phase B: o = q @ [P0;P1] as K=128 GEMM, 1024 blocks, q via
//    global_load_lds + XOR swizzle, ktv frags straight from global
//  - GEMMs / preps identical to R5 (passed, 0 bank conflicts)
//
// Workspace (MB offsets): 0 Wqkv(1.5) | 2 Wp(.5) | 3 W1(2) | 5 W2(2) | 7 BN |
//   8 xb(16.8)->x1 | 25 qb(16.8, o aliases) | 42 kb | 59 vb | 76 h(67.1)->143 |
//   150 ktvB(2)

typedef __attribute__((ext_vector_type(8))) short short8;
typedef __attribute__((ext_vector_type(4))) short short4v;
typedef __attribute__((ext_vector_type(4))) float f32x4;
typedef __attribute__((ext_vector_type(4))) unsigned int uint4v;

#define MFMA_BF16 __builtin_amdgcn_mfma_f32_16x16x32_bf16

__device__ __forceinline__ float bf2f(unsigned short u) {
    return __uint_as_float(((unsigned int)u) << 16);
}
__device__ __forceinline__ unsigned short f2bf(float f) {
    unsigned int b = __float_as_uint(f);
    return (unsigned short)((b + 0x7fffu + ((b >> 16) & 1u)) >> 16);
}
__device__ __forceinline__ void gl_lds16(const void* g, void* l) {
    __builtin_amdgcn_global_load_lds(
        (const __attribute__((address_space(1))) void*)g,
        (__attribute__((address_space(3))) void*)l, 16, 0, 0);
}

// ---------------- BN fold ----------------
__global__ __launch_bounds__(256) void prep_bn(
    const float* __restrict__ bias, const float* __restrict__ g,
    const float* __restrict__ be,   const float* __restrict__ m,
    const float* __restrict__ v,
    float* __restrict__ sc, float* __restrict__ sh, int n)
{
    int i = blockIdx.x * 256 + threadIdx.x;
    if (i < n) {
        float s = g[i] * rsqrtf(v[i] + 1e-5f);
        sc[i] = s;
        sh[i] = (bias[i] - m[i]) * s + be[i];
    }
}

// ---------------- x -> bf16 ----------------
__global__ __launch_bounds__(256) void to_bf16(
    const float* __restrict__ in, unsigned short* __restrict__ out, int n8)
{
    int i = blockIdx.x * 256 + threadIdx.x;
    if (i >= n8) return;
    const float4* p = (const float4*)in + (size_t)i * 2;
    float4 a = p[0], b = p[1];
    short8 r = {(short)f2bf(a.x), (short)f2bf(a.y), (short)f2bf(a.z), (short)f2bf(a.w),
                (short)f2bf(b.x), (short)f2bf(b.y), (short)f2bf(b.z), (short)f2bf(b.w)};
    ((short8*)out)[i] = r;
}

// -------- pack W (NxK fp32) into MFMA B-fragment order --------
__global__ __launch_bounds__(256) void prep_w(
    const float* __restrict__ W, unsigned short* __restrict__ ph, int N, int K)
{
    int tid = blockIdx.x * 256 + threadIdx.x;
    int KC = K >> 5;
    int total = (N >> 4) * KC * 64;
    if (tid >= total) return;
    int lane = tid & 63;
    int blk  = tid >> 6;
    int kc   = blk % KC;
    int n16  = blk / KC;
    int n  = (n16 << 4) + (lane & 15);
    int k0 = (kc << 5) + ((lane >> 4) << 3);
    const float* src = W + (size_t)n * K + k0;
    size_t dst = ((size_t)blk << 9) + (size_t)lane * 8;
#pragma unroll
    for (int j = 0; j < 8; ++j) ph[dst + j] = f2bf(src[j]);
}

// ---------------- bf16 GEMM + BN + ReLU (+ residual) ---------------- (as R5)
template<int NT, int RESMODE, int OUTMODE>
__global__ __launch_bounds__(256) void gemm_bf16(
    const unsigned short* __restrict__ Ag, const unsigned short* __restrict__ Wg,
    const float* __restrict__ sc, const float* __restrict__ sh,
    const float* __restrict__ resf, const unsigned short* __restrict__ resb,
    float* __restrict__ outf, unsigned short* __restrict__ outb,
    unsigned short* __restrict__ oq, unsigned short* __restrict__ ok2,
    unsigned short* __restrict__ ov, int M, int N, int K)
{
    constexpr int NF = NT / 32;
    __shared__ unsigned short As[128 * 32];

    const int t    = threadIdx.x;
    const int lane = t & 63;
    const int w    = t >> 6;
    const int wm   = w >> 1, wn = w & 1;
    const int KC   = K >> 5;

    const int nx  = gridDim.x;
    const int nwg = nx * gridDim.y;
    int bid = blockIdx.y * nx + blockIdx.x;
    bid = (bid & 7) * (nwg >> 3) + (bid >> 3);
    const int m0 = (bid / nx) * 128;
    const int n0 = (bid % nx) * NT;

    const int sr  = lane >> 2;
    const int kbu = (lane & 3) ^ ((lane >> 3) & 3);
    const unsigned short* sA0 = Ag + (size_t)(m0 + w * 32 + sr) * K + kbu * 8;
    const unsigned short* sA1 = sA0 + (size_t)16 * K;
    unsigned short* dA0 = &As[(w * 32) * 32];
    unsigned short* dA1 = &As[(w * 32 + 16) * 32];

    const unsigned short* pB[NF];
#pragma unroll
    for (int nf = 0; nf < NF; ++nf) {
        const int n16 = (n0 >> 4) + wn * (NT / 32) + nf;
        pB[nf] = Wg + (((size_t)n16 * KC) << 9) + (size_t)lane * 8;
    }

    const int fr = lane & 15, fk = lane >> 4;
    const int funit = fk ^ ((fr >> 1) & 3);
    int aoff[4];
#pragma unroll
    for (int mi = 0; mi < 4; ++mi)
        aoff[mi] = (wm * 64 + mi * 16 + fr) * 32 + funit * 8;

    f32x4 acc[4][NF];
#pragma unroll
    for (int i = 0; i < 4; ++i)
#pragma unroll
        for (int j = 0; j < NF; ++j) acc[i][j] = f32x4{0.f, 0.f, 0.f, 0.f};

    for (int kc = 0; kc < KC; ++kc) {
        __syncthreads();
        gl_lds16(sA0, dA0); gl_lds16(sA1, dA1);
        sA0 += 32; sA1 += 32;

        short8 bh[NF];
#pragma unroll
        for (int nf = 0; nf < NF; ++nf) {
            bh[nf] = *(const short8*)pB[nf];
            pB[nf] += 512;
        }
        __syncthreads();

        short8 ah[4];
#pragma unroll
        for (int mi = 0; mi < 4; ++mi) ah[mi] = *(const short8*)&As[aoff[mi]];
#pragma unroll
        for (int mi = 0; mi < 4; ++mi)
#pragma unroll
            for (int nf = 0; nf < NF; ++nf)
                acc[mi][nf] = MFMA_BF16(ah[mi], bh[nf], acc[mi][nf], 0, 0, 0);
    }

    const int erow4 = fk * 4;
#pragma unroll
    for (int nf = 0; nf < NF; ++nf) {
        const int col = n0 + wn * (NT / 2) + nf * 16 + fr;
        const float scv = sc[col], shv = sh[col];
        unsigned short* qsplit = nullptr;
        int lc = 0;
        if (OUTMODE == 2) {
            const int tsel = col >> 9;
            qsplit = (tsel == 0) ? oq : (tsel == 1) ? ok2 : ov;
            lc = col & 511;
        }
#pragma unroll
        for (int mi = 0; mi < 4; ++mi) {
            const int rbase = m0 + wm * 64 + mi * 16 + erow4;
#pragma unroll
            for (int r = 0; r < 4; ++r) {
                const size_t row = (size_t)(rbase + r);
                float z = fmaf(acc[mi][nf][r], scv, shv);
                z = fmaxf(z, 0.f);
                if (RESMODE == 1) z += resf[row * N + col];
                if (RESMODE == 2) z += bf2f(resb[row * N + col]);
                if (OUTMODE == 0)      outb[row * N + col] = f2bf(z);
                else if (OUTMODE == 1) outf[row * N + col] = z;
                else                   qsplit[row * 512 + lc] = f2bf(z);
            }
        }
    }
}

// ---------------- attn phase A: partial ktv, packed B-frag emit ----------------
// grid 256 x 64 threads. block = (bh, half): P = k[nrange]^T @ v[nrange] (64x64),
// emitted bf16 * 0.125 in B-fragment order at ktvB[bh], frag blocks (j16, 2*half+dcl).
__global__ __launch_bounds__(64) void attn_kv(
    const unsigned short* __restrict__ k, const unsigned short* __restrict__ v,
    unsigned short* __restrict__ ktvB)
{
    __shared__ unsigned short kN[32 * 66];   // padded: row stride 33 dwords
    __shared__ unsigned short vN[32 * 66];
    __shared__ float red[64 * 65];

    const int l  = threadIdx.x;
    const int bh = blockIdx.x >> 1;
    const int h1 = blockIdx.x & 1;
    const int b = bh >> 3, h = bh & 7;
    const int c8 = l & 7;          // load chunk col
    const int rh = l >> 3;         // load row-in-8
    const int c  = l & 15, nh = l >> 4;

    f32x4 acc[4][4];
#pragma unroll
    for (int i = 0; i < 4; ++i)
#pragma unroll
        for (int j = 0; j < 4; ++j) acc[i][j] = f32x4{0.f, 0.f, 0.f, 0.f};

    const size_t gbase = ((size_t)b * 1024 + (size_t)h1 * 512) * 512 + (size_t)h * 64;

    for (int t = 0; t < 16; ++t) {
        short8 kr[4], vr[4];
#pragma unroll
        for (int q = 0; q < 4; ++q) {
            const int n = 8 * q + rh;
            const size_t ga = gbase + (size_t)(t * 32 + n) * 512 + c8 * 8;
            kr[q] = *(const short8*)(k + ga);
            vr[q] = *(const short8*)(v + ga);
        }
        __syncthreads();   // prior frag reads drained before overwrite
#pragma unroll
        for (int q = 0; q < 4; ++q) {
            const int n = 8 * q + rh;
            unsigned int* pk = (unsigned int*)&kN[n * 66 + c8 * 8]; // 4B-aligned
            unsigned int* pv = (unsigned int*)&vN[n * 66 + c8 * 8];
            uint4v ku = *(const uint4v*)&kr[q];
            uint4v vu = *(const uint4v*)&vr[q];
#pragma unroll
            for (int w2 = 0; w2 < 4; ++w2) { pk[w2] = ku[w2]; pv[w2] = vu[w2]; }
        }
        __syncthreads();   // writes visible before gathers

        short8 aF[4], bF[4];
#pragma unroll
        for (int it = 0; it < 4; ++it)
#pragma unroll
            for (int jj = 0; jj < 8; ++jj)
                aF[it][jj] = (short)kN[(8 * nh + jj) * 66 + it * 16 + c];
#pragma unroll
        for (int jt = 0; jt < 4; ++jt)
#pragma unroll
            for (int jj = 0; jj < 8; ++jj)
                bF[jt][jj] = (short)vN[(8 * nh + jj) * 66 + jt * 16 + c];
#pragma unroll
        for (int it = 0; it < 4; ++it)
#pragma unroll
            for (int jt = 0; jt < 4; ++jt)
                acc[it][jt] = MFMA_BF16(aF[it], bF[jt], acc[it][jt], 0, 0, 0);
    }

    // acc -> red (fp32), rows i = ktv row (k's d), cols j (v's d)
#pragma unroll
    for (int it = 0; it < 4; ++it)
#pragma unroll
        for (int jt = 0; jt < 4; ++jt)
#pragma unroll
            for (int r = 0; r < 4; ++r)
                red[(it * 16 + nh * 4 + r) * 65 + jt * 16 + c] = acc[it][jt][r];
    __syncthreads();

    // emit 8 frag blocks (j16 0..3, dcl 0..1) scaled by 0.125, bf16
    unsigned short* dstb = ktvB + (size_t)bh * 8192;
#pragma unroll
    for (int j16 = 0; j16 < 4; ++j16)
#pragma unroll
        for (int dcl = 0; dcl < 2; ++dcl) {
            short8 o8;
#pragma unroll
            for (int jj = 0; jj < 8; ++jj)
                o8[jj] = (short)f2bf(red[(dcl * 32 + 8 * nh + jj) * 65 + j16 * 16 + c] * 0.125f);
            *(short8*)(dstb + (size_t)(j16 * 4 + (2 * h1 + dcl)) * 512 + l * 8) = o8;
        }
}

// ---------------- attn phase B: o = relu(q @ [P0;P1]) ----------------
// grid 1024 x 256 threads. block = (bh, mt): 128 q-rows x 64 cols, K=128.
// o aliases q (block-exclusive rows x head-cols).
__global__ __launch_bounds__(256) void attn_qo(
    const unsigned short* __restrict__ q, const unsigned short* __restrict__ ktvB,
    unsigned short* __restrict__ o)
{
    __shared__ unsigned short qS[128 * 64];

    int bid = blockIdx.x;
    bid = (bid & 7) * 128 + (bid >> 3);    // bijective XCD swizzle (1024 = 8*128)
    const int bh = bid >> 3, mt = bid & 7;
    const int b = bh >> 3, h = bh & 7;
    const size_t Mbase = (size_t)b * 1024 + (size_t)mt * 128;
    const int t = threadIdx.x, l = t & 63, w = t >> 6;
    const int c = l & 15, nh = l >> 4;

    // stage q-tile [128][64] via gl_lds, chunk XOR-swizzled source
#pragma unroll
    for (int qq = 0; qq < 4; ++qq) {
        const int r  = qq * 32 + w * 8 + (l >> 3);
        const int cl = (l & 7) ^ (r & 7);
        gl_lds16(q + (Mbase + r) * 512 + h * 64 + cl * 8,
                 &qS[(qq * 32 + w * 8) * 64]);
    }
    __syncthreads();

    const unsigned short* pB = ktvB + (size_t)bh * 8192 + (size_t)l * 8;

    f32x4 acc[2][4];
#pragma unroll
    for (int i = 0; i < 2; ++i)
#pragma unroll
        for (int j = 0; j < 4; ++j) acc[i][j] = f32x4{0.f, 0.f, 0.f, 0.f};

#pragma unroll
    for (int ks = 0; ks < 4; ++ks) {
        short8 aF[2], bF[4];
#pragma unroll
        for (int it = 0; it < 2; ++it) {
            const int ra   = w * 32 + it * 16 + c;
            const int phys = (((ks & 1) * 4) + nh) ^ (c & 7);   // (ra&7)==(c&7)
            aF[it] = *(const short8*)&qS[ra * 64 + phys * 8];
        }
#pragma unroll
        for (int jt = 0; jt < 4; ++jt)
            bF[jt] = *(const short8*)(pB + (size_t)(jt * 4 + ks) * 512);
#pragma unroll
        for (int it = 0; it < 2; ++it)
#pragma unroll
            for (int jt = 0; jt < 4; ++jt)
                acc[it][jt] = MFMA_BF16(aF[it], bF[jt], acc[it][jt], 0, 0, 0);
    }

#pragma unroll
    for (int it = 0; it < 2; ++it)
#pragma unroll
        for (int jt = 0; jt < 4; ++jt)
#pragma unroll
            for (int r = 0; r < 4; ++r) {
                const size_t row = Mbase + w * 32 + it * 16 + nh * 4 + r;
                o[row * 512 + h * 64 + jt * 16 + c] =
                    f2bf(fmaxf(acc[it][jt][r], 0.f));
            }
}

extern "C" void kernel_launch(void* const* d_in, const int* in_sizes, int n_in,
                              void* d_out, int out_size, void* d_ws, size_t ws_size,
                              hipStream_t stream)
{
    (void)in_sizes; (void)n_in; (void)out_size; (void)ws_size;
    const float* x = (const float*)d_in[0];
    auto P = [&](int i) { return (const float*)d_in[i]; };

    char* wsb = (char*)d_ws;
    const size_t MB = 1024 * 1024;
    auto US = [&](size_t off) { return (unsigned short*)(wsb + off); };

    unsigned short* Wqkv = US(0);
    unsigned short* Wp   = US(2 * MB);
    unsigned short* W1   = US(3 * MB);
    unsigned short* W2   = US(5 * MB);

    float* bn = (float*)(wsb + 7 * MB);
    float* sc_qkv = bn;          float* sh_qkv = bn + 1536;
    float* sc_p = bn + 3072;     float* sh_p = bn + 3584;
    float* sc_1 = bn + 4096;     float* sh_1 = bn + 6144;
    float* sc_2 = bn + 8192;     float* sh_2 = bn + 8704;

    unsigned short* xb = US(8 * MB);
    unsigned short* qb = US(25 * MB);      // o aliases q
    unsigned short* kb = US(42 * MB);
    unsigned short* vb = US(59 * MB);
    unsigned short* hb = US(76 * MB);
    unsigned short* x1 = xb;
    unsigned short* ktvB = US(150 * MB);   // 2 MB packed ktv frags

    prep_bn<<<2, 256, 0, stream>>>(P(2),  P(3),  P(4),  P(5),  P(6),  sc_qkv,        sh_qkv,        512);
    prep_bn<<<2, 256, 0, stream>>>(P(8),  P(9),  P(10), P(11), P(12), sc_qkv + 512,  sh_qkv + 512,  512);
    prep_bn<<<2, 256, 0, stream>>>(P(14), P(15), P(16), P(17), P(18), sc_qkv + 1024, sh_qkv + 1024, 512);
    prep_bn<<<2, 256, 0, stream>>>(P(20), P(21), P(22), P(23), P(24), sc_p, sh_p, 512);
    prep_bn<<<8, 256, 0, stream>>>(P(26), P(27), P(28), P(29), P(30), sc_1, sh_1, 2048);
    prep_bn<<<2, 256, 0, stream>>>(P(32), P(33), P(34), P(35), P(36), sc_2, sh_2, 512);

    to_bf16<<<4096, 256, 0, stream>>>(x, xb, 16384 * 512 / 8);

    prep_w<<<128, 256, 0, stream>>>(P(1),  Wqkv,          512, 512);
    prep_w<<<128, 256, 0, stream>>>(P(7),  Wqkv + 262144, 512, 512);
    prep_w<<<128, 256, 0, stream>>>(P(13), Wqkv + 524288, 512, 512);
    prep_w<<<128, 256, 0, stream>>>(P(19), Wp, 512, 512);
    prep_w<<<512, 256, 0, stream>>>(P(25), W1, 2048, 512);
    prep_w<<<512, 256, 0, stream>>>(P(31), W2, 512, 2048);

    const dim3 blk(256);

    gemm_bf16<128, 0, 2><<<dim3(12, 128), blk, 0, stream>>>(
        xb, Wqkv, sc_qkv, sh_qkv, nullptr, nullptr,
        nullptr, nullptr, qb, kb, vb, 16384, 1536, 512);

    attn_kv<<<256, 64, 0, stream>>>(kb, vb, ktvB);
    attn_qo<<<1024, blk, 0, stream>>>(qb, ktvB, qb);   // o -> qb

    gemm_bf16<64, 1, 0><<<dim3(8, 128), blk, 0, stream>>>(
        qb, Wp, sc_p, sh_p, x, nullptr,
        nullptr, x1, nullptr, nullptr, nullptr, 16384, 512, 512);

    gemm_bf16<128, 0, 0><<<dim3(16, 128), blk, 0, stream>>>(
        x1, W1, sc_1, sh_1, nullptr, nullptr,
        nullptr, hb, nullptr, nullptr, nullptr, 16384, 2048, 512);

    gemm_bf16<64, 2, 1><<<dim3(8, 128), blk, 0, stream>>>(
        hb, W2, sc_2, sh_2, nullptr, x1,
        (float*)d_out, nullptr, nullptr, nullptr, nullptr, 16384, 512, 2048);
}